// Round 1
// baseline (420.652 us; speedup 1.0000x reference)
//
#include <hip/hip_runtime.h>
#include <hip/hip_bf16.h>

typedef unsigned short u16;
typedef unsigned int u32;
typedef unsigned char u8;

#define M_DIM 8192   // B*S = 4*2048
#define K_DIM 4096   // I
#define N_DIM 4096   // O
#define GROUPS 64    // I / GROUP_SIZE

typedef int intx4 __attribute__((ext_vector_type(4)));

__device__ __forceinline__ void gload_lds16(const void* g, void* l) {
  __builtin_amdgcn_global_load_lds(
      (const __attribute__((address_space(1))) void*)g,
      (__attribute__((address_space(3))) void*)l, 16, 0, 0);
}

__device__ __forceinline__ float block_absmax(float amax, float* red) {
  // wave butterfly then cross-wave via LDS (4 waves, 256 threads)
#pragma unroll
  for (int off = 32; off; off >>= 1)
    amax = fmaxf(amax, __shfl_xor(amax, off, 64));
  const int wave = threadIdx.x >> 6;
  if ((threadIdx.x & 63) == 0) red[wave] = amax;
  __syncthreads();
  return fmaxf(fmaxf(red[0], red[1]), fmaxf(red[2], red[3]));
}

__device__ __forceinline__ u32 pack4(const float* v, float inv) {
  u32 r = 0;
#pragma unroll
  for (int i = 0; i < 4; ++i) {
    int q = (int)__builtin_rintf(v[i] * inv);
    q = q > 127 ? 127 : (q < -127 ? -127 : q);
    r |= ((u32)(u8)(char)q) << (8 * i);
  }
  return r;
}

// ---- kernel 1: per-row symmetric int8 quant of x*cs; sx[m]=absmax/127 ----
__global__ __launch_bounds__(256) void prep_x(
    const float* __restrict__ x, const float* __restrict__ cs,
    u8* __restrict__ xq, float* __restrict__ sx) {
  __shared__ float red[4];
  const size_t m = blockIdx.x;
  const float* xr = x + m * K_DIM;
  const int base = threadIdx.x * 16;   // 16 consecutive elems per thread
  float v[16];
  float amax = 0.f;
#pragma unroll
  for (int j = 0; j < 4; ++j) {
    float4 xv = *(const float4*)(xr + base + j * 4);
    float4 cv = *(const float4*)(cs + base + j * 4);
    v[j * 4 + 0] = xv.x * cv.x;
    v[j * 4 + 1] = xv.y * cv.y;
    v[j * 4 + 2] = xv.z * cv.z;
    v[j * 4 + 3] = xv.w * cv.w;
#pragma unroll
    for (int i = 0; i < 4; ++i) amax = fmaxf(amax, fabsf(v[j * 4 + i]));
  }
  amax = block_absmax(amax, red);
  amax = fmaxf(amax, 1e-20f);
  const float inv = 127.0f / amax;
  uint4 p;
  p.x = pack4(v + 0, inv);
  p.y = pack4(v + 4, inv);
  p.z = pack4(v + 8, inv);
  p.w = pack4(v + 12, inv);
  *(uint4*)(xq + m * K_DIM + base) = p;
  if (threadIdx.x == 0) sx[m] = amax * (1.0f / 127.0f);
}

// ---- kernel 2: dequant+permute one weight row, int8 quant; sw[o] ----
__global__ __launch_bounds__(256) void prep_w(
    const u32* __restrict__ qw, const int* __restrict__ perm,
    const float* __restrict__ scales, const float* __restrict__ zeros,
    u8* __restrict__ wq, float* __restrict__ sw) {
  __shared__ float rowbuf[K_DIM];   // 16 KB
  __shared__ float red[4];
  const int o = blockIdx.x;
  const u32* qrow = qw + (size_t)o * (K_DIM / 8);
  float amax = 0.f;
#pragma unroll
  for (int it = 0; it < 2; ++it) {
    int t = it * 256 + threadIdx.x;   // word index 0..511
    u32 q = qrow[t];
    int g = t >> 3;
    float s = scales[o * GROUPS + g];
    float z = zeros[o * GROUPS + g];
#pragma unroll
    for (int n = 0; n < 8; ++n) {
      float v = (float)((q >> (4 * n)) & 15u) * s + z;
      amax = fmaxf(amax, fabsf(v));
      rowbuf[perm[t * 8 + n]] = v;
    }
  }
  __syncthreads();   // rowbuf complete
  amax = block_absmax(amax, red);   // contains its own __syncthreads
  amax = fmaxf(amax, 1e-20f);
  const float inv = 127.0f / amax;
  const int base = threadIdx.x * 16;
  uint4 p;
  p.x = pack4(rowbuf + base + 0, inv);
  p.y = pack4(rowbuf + base + 4, inv);
  p.z = pack4(rowbuf + base + 8, inv);
  p.w = pack4(rowbuf + base + 12, inv);
  *(uint4*)(wq + (size_t)o * K_DIM + base) = p;
  if (threadIdx.x == 0) sw[o] = amax * (1.0f / 127.0f);
}

// ---- kernel 3: out[m][o] = sx[m]*sw[o]*(Xq @ Wq^T)[m][o] + bias[o] ----
// 256x256 tile, BK=64, 8 waves (2M x 4N), per-wave 128x64 output.
// TRI-buffered LDS (96 KB) with 2-tile-deep prefetch and COUNTED
// s_waitcnt vmcnt(4) + one raw s_barrier per K-tile: the main loop never
// drains vmcnt to 0 (T3+T4), so staging loads stay in flight across
// barriers. vmcnt-before-barrier turns each wave's private count into a
// collective guarantee. Swizzle: physical 16B slot p of row r holds global
// chunk p ^ ((r>>1)&3) (verified conflict-free: SQ_LDS_BANK_CONFLICT==0);
// frag reads un-swizzle with qs = q ^ ((lr>>1)&3) (row base is a multiple
// of 16, so only lr contributes).
#define BM 256
#define BN 256
#define BK 64
#define KTILES (K_DIM / BK)   // 64

__global__ __launch_bounds__(512, 2) void gemm_i8(
    const u8* __restrict__ A, const u8* __restrict__ B,
    const float* __restrict__ sx, const float* __restrict__ sw,
    const float* __restrict__ bias, float* __restrict__ out) {
  __shared__ __align__(16) u8 As[3][BM * BK];   // 3 x 16 KB
  __shared__ __align__(16) u8 Bs[3][BN * BK];   // 3 x 16 KB
  const int tid = threadIdx.x;
  const int lane = tid & 63;
  const int wave = tid >> 6;           // 0..7
  const int wm = wave >> 2;            // 0..1 -> 128 M-rows each
  const int wn = wave & 3;             // 0..3 -> 64 N-cols each
  const int q = lane >> 4, lr = lane & 15;
  const int qs = q ^ ((lr >> 1) & 3);  // physical 16B slot for frag reads
  const int blockN = blockIdx.x * BN;
  const int blockM = blockIdx.y * BM;

  const char* Abase = (const char*)(A + (size_t)blockM * K_DIM);
  const char* Bbase = (const char*)(B + (size_t)blockN * K_DIM);

  // staging: 1024 chunks per matrix per tile, 2 per thread
  const int c0 = tid, c1 = tid + 512;
  const int r0 = c0 >> 2, kc0 = (c0 & 3) ^ ((c0 >> 3) & 3);
  const int r1 = c1 >> 2, kc1 = (c1 & 3) ^ ((c1 >> 3) & 3);

  intx4 acc[8][4];
#pragma unroll
  for (int i = 0; i < 8; ++i)
#pragma unroll
    for (int j = 0; j < 4; ++j) acc[i][j] = (intx4)0;

  auto stage = [&](int t, int b) {
    const size_t koff = (size_t)t * BK;
    gload_lds16(Abase + (size_t)r0 * K_DIM + koff + kc0 * 16, &As[b][c0 * 16]);
    gload_lds16(Abase + (size_t)r1 * K_DIM + koff + kc1 * 16, &As[b][c1 * 16]);
    gload_lds16(Bbase + (size_t)r0 * K_DIM + koff + kc0 * 16, &Bs[b][c0 * 16]);
    gload_lds16(Bbase + (size_t)r1 * K_DIM + koff + kc1 * 16, &Bs[b][c1 * 16]);
  };

  auto compute = [&](int b) {
    intx4 af[8], bf[4];
#pragma unroll
    for (int mi = 0; mi < 8; ++mi)
      af[mi] = *(const intx4*)&As[b][(wm * 128 + mi * 16 + lr) * 64 + qs * 16];
#pragma unroll
    for (int ni = 0; ni < 4; ++ni)
      bf[ni] = *(const intx4*)&Bs[b][(wn * 64 + ni * 16 + lr) * 64 + qs * 16];
    __builtin_amdgcn_s_setprio(1);
#pragma unroll
    for (int mi = 0; mi < 8; ++mi)
#pragma unroll
      for (int ni = 0; ni < 4; ++ni)
        acc[mi][ni] = __builtin_amdgcn_mfma_i32_16x16x64_i8(
            af[mi], bf[ni], acc[mi][ni], 0, 0, 0);
    __builtin_amdgcn_s_setprio(0);
  };

  // prologue: tiles 0 and 1 in flight; certify tile 0 (leave tile 1 flying)
  stage(0, 0);
  stage(1, 1);
  asm volatile("s_waitcnt vmcnt(4)\n\ts_barrier" ::: "memory");

  int bc = 0;   // compute buffer for tile t
  int bs = 2;   // stage buffer for tile t+2
  for (int t = 0; t < KTILES - 2; ++t) {
    stage(t + 2, bs);
    compute(bc);
    // certify tile t+1 landed (t+2's 4 loads stay in flight), then join
    asm volatile("s_waitcnt vmcnt(4)\n\ts_barrier" ::: "memory");
    bc = (bc == 2) ? 0 : bc + 1;
    bs = (bs == 2) ? 0 : bs + 1;
  }
  // epilogue of the pipeline: drain 4 -> 0
  compute(bc);                                       // tile KTILES-2
  asm volatile("s_waitcnt vmcnt(0)\n\ts_barrier" ::: "memory");
  bc = (bc == 2) ? 0 : bc + 1;
  compute(bc);                                       // tile KTILES-1

  // epilogue: C/D layout col = lane&15, row = quad*4 + reg (dtype-independent)
#pragma unroll
  for (int ni = 0; ni < 4; ++ni) {
    const int col = blockN + wn * 64 + ni * 16 + lr;
    const float swv = sw[col];
    const float bv = bias[col];
#pragma unroll
    for (int mi = 0; mi < 8; ++mi) {
      const int row0 = blockM + wm * 128 + mi * 16 + q * 4;
#pragma unroll
      for (int r = 0; r < 4; ++r) {
        const float s = sx[row0 + r] * swv;
        out[(size_t)(row0 + r) * N_DIM + col] = (float)acc[mi][ni][r] * s + bv;
      }
    }
  }
}

extern "C" void kernel_launch(void* const* d_in, const int* in_sizes, int n_in,
                              void* d_out, int out_size, void* d_ws, size_t ws_size,
                              hipStream_t stream) {
  const float* x      = (const float*)d_in[0];
  const float* cs     = (const float*)d_in[1];
  const u32*   qw     = (const u32*)d_in[2];
  const int*   perm   = (const int*)d_in[3];
  const float* scales = (const float*)d_in[4];
  const float* zeros  = (const float*)d_in[5];
  const float* bias   = (const float*)d_in[6];
  float* out = (float*)d_out;

  u8* xq = (u8*)d_ws;                               // 32 MiB: M*K i8
  u8* wq = xq + (size_t)M_DIM * K_DIM;              // 16 MiB: N*K i8 (permuted)
  float* sx = (float*)(wq + (size_t)N_DIM * K_DIM); // 32 KiB
  float* sw = sx + M_DIM;                           // 16 KiB

  hipLaunchKernelGGL(prep_x, dim3(M_DIM), dim3(256), 0, stream, x, cs, xq, sx);
  hipLaunchKernelGGL(prep_w, dim3(N_DIM), dim3(256), 0, stream,
                     qw, perm, scales, zeros, wq, sw);
  hipLaunchKernelGGL(gemm_i8, dim3(N_DIM / BN, M_DIM / BM), dim3(512), 0,
                     stream, xq, wq, sx, sw, bias, out);
}

// Round 2
// 414.396 us; speedup vs baseline: 1.0151x; 1.0151x over previous
//
#include <hip/hip_runtime.h>
#include <hip/hip_bf16.h>

typedef unsigned short u16;
typedef unsigned int u32;
typedef unsigned char u8;

#define M_DIM 8192   // B*S = 4*2048
#define K_DIM 4096   // I
#define N_DIM 4096   // O
#define GROUPS 64    // I / GROUP_SIZE

typedef int intx4 __attribute__((ext_vector_type(4)));

__device__ __forceinline__ void gload_lds16(const void* g, void* l) {
  __builtin_amdgcn_global_load_lds(
      (const __attribute__((address_space(1))) void*)g,
      (__attribute__((address_space(3))) void*)l, 16, 0, 0);
}

__device__ __forceinline__ float block_absmax(float amax, float* red) {
#pragma unroll
  for (int off = 32; off; off >>= 1)
    amax = fmaxf(amax, __shfl_xor(amax, off, 64));
  const int wave = threadIdx.x >> 6;
  if ((threadIdx.x & 63) == 0) red[wave] = amax;
  __syncthreads();
  return fmaxf(fmaxf(red[0], red[1]), fmaxf(red[2], red[3]));
}

__device__ __forceinline__ u32 pack4(const float* v, float inv) {
  u32 r = 0;
#pragma unroll
  for (int i = 0; i < 4; ++i) {
    int q = (int)__builtin_rintf(v[i] * inv);
    q = q > 127 ? 127 : (q < -127 ? -127 : q);
    r |= ((u32)(u8)(char)q) << (8 * i);
  }
  return r;
}

// ---- kernel 1: x*cs, K-permute BY GATHER, per-row int8 quant ----
// The q_perm is a bijection on the K axis; applying it to BOTH operands
// leaves the i32 dot product exactly invariant. So xq[m][j] =
// quant(x[m][perm[j]]*cs[perm[j]]) and W stays in natural nibble order.
// Row staged in LDS strided (conflict-free b32), gathered randomly
// (~2x conflict cost, far cheaper than prep_w's old random scatter).
__global__ __launch_bounds__(256) void prep_x(
    const float* __restrict__ x, const float* __restrict__ cs,
    const int* __restrict__ perm, u8* __restrict__ xq, float* __restrict__ sx) {
  __shared__ float row[K_DIM];   // 16 KB, indexed by element
  __shared__ float red[4];
  const size_t m = blockIdx.x;
  const float* xr = x + m * K_DIM;
  const int t = threadIdx.x;
  float amax = 0.f;
#pragma unroll
  for (int j = 0; j < 16; ++j) {
    const int idx = j * 256 + t;          // coalesced, conflict-free LDS write
    float v = xr[idx] * cs[idx];
    amax = fmaxf(amax, fabsf(v));
    row[idx] = v;
  }
  amax = block_absmax(amax, red);         // syncthreads inside orders row[]
  amax = fmaxf(amax, 1e-20f);
  const float inv = 127.0f / amax;
  const int base = t * 16;
  int4 p0 = *(const int4*)(perm + base + 0);
  int4 p1 = *(const int4*)(perm + base + 4);
  int4 p2 = *(const int4*)(perm + base + 8);
  int4 p3 = *(const int4*)(perm + base + 12);
  float g[16];
  g[0]  = row[p0.x]; g[1]  = row[p0.y]; g[2]  = row[p0.z]; g[3]  = row[p0.w];
  g[4]  = row[p1.x]; g[5]  = row[p1.y]; g[6]  = row[p1.z]; g[7]  = row[p1.w];
  g[8]  = row[p2.x]; g[9]  = row[p2.y]; g[10] = row[p2.z]; g[11] = row[p2.w];
  g[12] = row[p3.x]; g[13] = row[p3.y]; g[14] = row[p3.z]; g[15] = row[p3.w];
  uint4 pk;
  pk.x = pack4(g + 0, inv);
  pk.y = pack4(g + 4, inv);
  pk.z = pack4(g + 8, inv);
  pk.w = pack4(g + 12, inv);
  *(uint4*)(xq + m * K_DIM + base) = pk;
  if (t == 0) sx[m] = amax * (1.0f / 127.0f);
}

// ---- kernel 2: streaming dequant + int8 quant, NO permute, NO LDS ----
// thread t: words 2t,2t+1 -> elements [16t,16t+16), all in group t>>2.
__global__ __launch_bounds__(256) void prep_w(
    const u32* __restrict__ qw,
    const float* __restrict__ scales, const float* __restrict__ zeros,
    u8* __restrict__ wq, float* __restrict__ sw) {
  __shared__ float red[4];
  const int o = blockIdx.x;
  const u32* qrow = qw + (size_t)o * (K_DIM / 8);
  const int t = threadIdx.x;
  const float s = scales[o * GROUPS + (t >> 2)];
  const float z = zeros[o * GROUPS + (t >> 2)];
  uint2 w = *(const uint2*)(qrow + 2 * t);
  float v[16];
  float amax = 0.f;
#pragma unroll
  for (int n = 0; n < 8; ++n) {
    v[n]     = (float)((w.x >> (4 * n)) & 15u) * s + z;
    v[8 + n] = (float)((w.y >> (4 * n)) & 15u) * s + z;
    amax = fmaxf(amax, fmaxf(fabsf(v[n]), fabsf(v[8 + n])));
  }
  amax = block_absmax(amax, red);
  amax = fmaxf(amax, 1e-20f);
  const float inv = 127.0f / amax;
  uint4 p;
  p.x = pack4(v + 0, inv);
  p.y = pack4(v + 4, inv);
  p.z = pack4(v + 8, inv);
  p.w = pack4(v + 12, inv);
  *(uint4*)(wq + (size_t)o * K_DIM + t * 16) = p;
  if (t == 0) sw[o] = amax * (1.0f / 127.0f);
}

// ---- kernel 3: 8-phase-template i8 GEMM ----
// 256x256 tile, BK=64, 8 waves (2M x 4N), per-wave 128x64 out.
// 4 phases per K-tile, each: {ds_read subtile + 1 global_load_lds ->
// raw s_barrier -> setprio(1) 8 MFMA setprio(0) -> s_barrier}.
// Counted s_waitcnt vmcnt(4) ONCE per K-tile (tri-buffer, 2 tiles in
// flight, never drained to 0 in the main loop). ds_reads are plain loads
// so the compiler keeps fine-grained lgkmcnt before first MFMA use.
// Swizzle: slot p of row r holds chunk p ^ ((r>>1)&3); reads un-swizzle
// with qs = q ^ ((lr>>1)&3) (verified conflict-free, counter == 0).
#define BM 256
#define BN 256
#define BK 64
#define KTILES (K_DIM / BK)   // 64

__global__ __launch_bounds__(512, 2) void gemm_i8(
    const u8* __restrict__ A, const u8* __restrict__ B,
    const float* __restrict__ sx, const float* __restrict__ sw,
    const float* __restrict__ bias, float* __restrict__ out) {
  __shared__ __align__(16) u8 As[3][BM * BK];   // 3 x 16 KB
  __shared__ __align__(16) u8 Bs[3][BN * BK];   // 3 x 16 KB
  const int tid = threadIdx.x;
  const int lane = tid & 63;
  const int wave = tid >> 6;
  const int wm = wave >> 2;            // 0..1
  const int wn = wave & 3;             // 0..3
  const int q = lane >> 4, lr = lane & 15;
  const int qs = q ^ ((lr >> 1) & 3);
  const int blockN = blockIdx.x * BN;
  const int blockM = blockIdx.y * BM;

  const char* Abase = (const char*)(A + (size_t)blockM * K_DIM);
  const char* Bbase = (const char*)(B + (size_t)blockN * K_DIM);

  // staging geometry: 1024 chunks per matrix per tile, 4 loads/thread/tile
  const int c0 = tid, c1 = tid + 512;
  const int kc0 = (c0 & 3) ^ ((c0 >> 3) & 3);
  const int kc1 = (c1 & 3) ^ ((c1 >> 3) & 3);
  const size_t gOff0 = (size_t)(c0 >> 2) * K_DIM + kc0 * 16;
  const size_t gOff1 = (size_t)(c1 >> 2) * K_DIM + kc1 * 16;
  const int dOff0 = c0 * 16, dOff1 = c1 * 16;

  // fragment base offsets within a buffer (+ mi*1024 / + ni*1024)
  const int aoff = (wm * 128 + lr) * 64 + qs * 16;
  const int boff = (wn * 64 + lr) * 64 + qs * 16;

  intx4 acc[8][4];
#pragma unroll
  for (int i = 0; i < 8; ++i)
#pragma unroll
    for (int j = 0; j < 4; ++j) acc[i][j] = (intx4)0;

  // prologue: tile0 -> buf0, tile1 -> buf1; certify tile0, leave tile1 flying
  gload_lds16(Abase + gOff0, &As[0][dOff0]);
  gload_lds16(Abase + gOff1, &As[0][dOff1]);
  gload_lds16(Bbase + gOff0, &Bs[0][dOff0]);
  gload_lds16(Bbase + gOff1, &Bs[0][dOff1]);
  gload_lds16(Abase + gOff0 + BK, &As[1][dOff0]);
  gload_lds16(Abase + gOff1 + BK, &As[1][dOff1]);
  gload_lds16(Bbase + gOff0 + BK, &Bs[1][dOff0]);
  gload_lds16(Bbase + gOff1 + BK, &Bs[1][dOff1]);
  asm volatile("s_waitcnt vmcnt(4)" ::: "memory");
  asm volatile("s_barrier" ::: "memory");

  int bc = 0, bs = 2;
  for (int t = 0; t < KTILES; ++t) {
    const u8* Ab = &As[bc][0];
    const u8* Bb = &Bs[bc][0];
    u8* Aw = &As[bs][0];
    u8* Bw = &Bs[bs][0];
    const size_t koff2 = (size_t)(t + 2) * BK;
    const bool pf = (t + 2 < KTILES);
    intx4 bf[4], a0, a1;

#define MFMA8(MI0, MI1)                                                     \
  __builtin_amdgcn_s_setprio(1);                                            \
  _Pragma("unroll") for (int ni = 0; ni < 4; ++ni)                          \
      acc[MI0][ni] = __builtin_amdgcn_mfma_i32_16x16x64_i8(                 \
          a0, bf[ni], acc[MI0][ni], 0, 0, 0);                               \
  _Pragma("unroll") for (int ni = 0; ni < 4; ++ni)                          \
      acc[MI1][ni] = __builtin_amdgcn_mfma_i32_16x16x64_i8(                 \
          a1, bf[ni], acc[MI1][ni], 0, 0, 0);                               \
  __builtin_amdgcn_s_setprio(0);

    // ---- phase 0: bf0..3 + a0,a1 | stage A part0 of t+2 ----
    bf[0] = *(const intx4*)(Bb + boff + 0 * 1024);
    bf[1] = *(const intx4*)(Bb + boff + 1 * 1024);
    bf[2] = *(const intx4*)(Bb + boff + 2 * 1024);
    bf[3] = *(const intx4*)(Bb + boff + 3 * 1024);
    a0 = *(const intx4*)(Ab + aoff + 0 * 1024);
    a1 = *(const intx4*)(Ab + aoff + 1 * 1024);
    if (pf) gload_lds16(Abase + gOff0 + koff2, Aw + dOff0);
    asm volatile("s_barrier" ::: "memory");
    MFMA8(0, 1)
    asm volatile("s_barrier" ::: "memory");

    // ---- phase 1: a2,a3 | stage A part1 ----
    a0 = *(const intx4*)(Ab + aoff + 2 * 1024);
    a1 = *(const intx4*)(Ab + aoff + 3 * 1024);
    if (pf) gload_lds16(Abase + gOff1 + koff2, Aw + dOff1);
    asm volatile("s_barrier" ::: "memory");
    MFMA8(2, 3)
    asm volatile("s_barrier" ::: "memory");

    // ---- phase 2: a4,a5 | stage B part0 ----
    a0 = *(const intx4*)(Ab + aoff + 4 * 1024);
    a1 = *(const intx4*)(Ab + aoff + 5 * 1024);
    if (pf) gload_lds16(Bbase + gOff0 + koff2, Bw + dOff0);
    asm volatile("s_barrier" ::: "memory");
    MFMA8(4, 5)
    asm volatile("s_barrier" ::: "memory");

    // ---- phase 3: a6,a7 | stage B part1 | tile-boundary counted vmcnt ----
    a0 = *(const intx4*)(Ab + aoff + 6 * 1024);
    a1 = *(const intx4*)(Ab + aoff + 7 * 1024);
    if (pf) gload_lds16(Bbase + gOff1 + koff2, Bw + dOff1);
    asm volatile("s_barrier" ::: "memory");
    MFMA8(6, 7)
    if (t < KTILES - 2) {
      asm volatile("s_waitcnt vmcnt(4)" ::: "memory");   // t+1 certified
    } else if (t == KTILES - 2) {
      asm volatile("s_waitcnt vmcnt(0)" ::: "memory");   // drain
    }
    if (t < KTILES - 1) asm volatile("s_barrier" ::: "memory");

    bc = (bc == 2) ? 0 : bc + 1;
    bs = (bs == 2) ? 0 : bs + 1;
#undef MFMA8
  }

  // epilogue: C/D layout col = lane&15, row = quad*4 + reg
#pragma unroll
  for (int ni = 0; ni < 4; ++ni) {
    const int col = blockN + wn * 64 + ni * 16 + lr;
    const float swv = sw[col];
    const float bv = bias[col];
#pragma unroll
    for (int mi = 0; mi < 8; ++mi) {
      const int row0 = blockM + wm * 128 + mi * 16 + q * 4;
#pragma unroll
      for (int r = 0; r < 4; ++r) {
        const float s = sx[row0 + r] * swv;
        out[(size_t)(row0 + r) * N_DIM + col] = (float)acc[mi][ni][r] * s + bv;
      }
    }
  }
}

extern "C" void kernel_launch(void* const* d_in, const int* in_sizes, int n_in,
                              void* d_out, int out_size, void* d_ws, size_t ws_size,
                              hipStream_t stream) {
  const float* x      = (const float*)d_in[0];
  const float* cs     = (const float*)d_in[1];
  const u32*   qw     = (const u32*)d_in[2];
  const int*   perm   = (const int*)d_in[3];
  const float* scales = (const float*)d_in[4];
  const float* zeros  = (const float*)d_in[5];
  const float* bias   = (const float*)d_in[6];
  float* out = (float*)d_out;

  u8* xq = (u8*)d_ws;                               // 32 MiB: M*K i8 (permuted)
  u8* wq = xq + (size_t)M_DIM * K_DIM;              // 16 MiB: N*K i8 (natural)
  float* sx = (float*)(wq + (size_t)N_DIM * K_DIM); // 32 KiB
  float* sw = sx + M_DIM;                           // 16 KiB

  hipLaunchKernelGGL(prep_x, dim3(M_DIM), dim3(256), 0, stream, x, cs, perm, xq, sx);
  hipLaunchKernelGGL(prep_w, dim3(N_DIM), dim3(256), 0, stream,
                     qw, scales, zeros, wq, sw);
  hipLaunchKernelGGL(gemm_i8, dim3(N_DIM / BN, M_DIM / BM), dim3(512), 0,
                     stream, xq, wq, sx, sw, bias, out);
}

// Round 3
// 388.541 us; speedup vs baseline: 1.0826x; 1.0665x over previous
//
#include <hip/hip_runtime.h>

typedef unsigned int u32;
typedef unsigned char u8;

#define M_DIM 8192   // B*S = 4*2048
#define K_DIM 4096   // I
#define N_DIM 4096   // O
#define GROUPS 64    // I / GROUP_SIZE

typedef int intx4 __attribute__((ext_vector_type(4)));
typedef int intx16 __attribute__((ext_vector_type(16)));

__device__ __forceinline__ void gload_lds16(const void* g, void* l) {
  __builtin_amdgcn_global_load_lds(
      (const __attribute__((address_space(1))) void*)g,
      (__attribute__((address_space(3))) void*)l, 16, 0, 0);
}

__device__ __forceinline__ float block_absmax(float amax, float* red) {
#pragma unroll
  for (int off = 32; off; off >>= 1)
    amax = fmaxf(amax, __shfl_xor(amax, off, 64));
  const int wave = threadIdx.x >> 6;
  if ((threadIdx.x & 63) == 0) red[wave] = amax;
  __syncthreads();
  return fmaxf(fmaxf(red[0], red[1]), fmaxf(red[2], red[3]));
}

__device__ __forceinline__ u32 pack4(const float* v, float inv) {
  u32 r = 0;
#pragma unroll
  for (int i = 0; i < 4; ++i) {
    int q = (int)__builtin_rintf(v[i] * inv);
    q = q > 127 ? 127 : (q < -127 ? -127 : q);
    r |= ((u32)(u8)(char)q) << (8 * i);
  }
  return r;
}

// ---- fused prep: one dispatch, 12288 blocks ----
// blocks [0, N_DIM): W path — dequant row o, SCATTER via perm into LDS
//   (wq[o][perm[j]] = nib_j * s + z), quantize to i8. Verified convention
//   from round 0: sum_i xq_nat[i]*wq[o][i] == reference.
// blocks [N_DIM, N_DIM+M_DIM): X path — x*cs in natural order, quantize.
// W-blocks dispatched FIRST so their LDS-bound waves overlap the X-blocks'
// BW-bound waves instead of serializing behind a kernel boundary.
__global__ __launch_bounds__(256) void prep_all(
    const float* __restrict__ x, const float* __restrict__ cs,
    const u32* __restrict__ qw, const int* __restrict__ perm,
    const float* __restrict__ scales, const float* __restrict__ zeros,
    u8* __restrict__ xq, u8* __restrict__ wq,
    float* __restrict__ sx, float* __restrict__ sw) {
  __shared__ float rowbuf[K_DIM];   // 16 KB (W path only)
  __shared__ float red[4];
  const int t = threadIdx.x;
  const int base = t * 16;
  if (blockIdx.x < N_DIM) {
    // ---- W path ----
    const int o = blockIdx.x;
    const u32* qrow = qw + (size_t)o * (K_DIM / 8);
    const float s = scales[o * GROUPS + (t >> 2)];
    const float z = zeros[o * GROUPS + (t >> 2)];
    uint2 w = *(const uint2*)(qrow + 2 * t);   // elements [16t, 16t+16)
    int4 p0 = *(const int4*)(perm + base + 0);
    int4 p1 = *(const int4*)(perm + base + 4);
    int4 p2 = *(const int4*)(perm + base + 8);
    int4 p3 = *(const int4*)(perm + base + 12);
    float v[16];
    float amax = 0.f;
#pragma unroll
    for (int n = 0; n < 8; ++n) {
      v[n]     = (float)((w.x >> (4 * n)) & 15u) * s + z;
      v[8 + n] = (float)((w.y >> (4 * n)) & 15u) * s + z;
      amax = fmaxf(amax, fmaxf(fabsf(v[n]), fabsf(v[8 + n])));
    }
    rowbuf[p0.x] = v[0];  rowbuf[p0.y] = v[1];
    rowbuf[p0.z] = v[2];  rowbuf[p0.w] = v[3];
    rowbuf[p1.x] = v[4];  rowbuf[p1.y] = v[5];
    rowbuf[p1.z] = v[6];  rowbuf[p1.w] = v[7];
    rowbuf[p2.x] = v[8];  rowbuf[p2.y] = v[9];
    rowbuf[p2.z] = v[10]; rowbuf[p2.w] = v[11];
    rowbuf[p3.x] = v[12]; rowbuf[p3.y] = v[13];
    rowbuf[p3.z] = v[14]; rowbuf[p3.w] = v[15];
    amax = block_absmax(amax, red);   // sync inside orders rowbuf too
    amax = fmaxf(amax, 1e-20f);
    const float inv = 127.0f / amax;
    uint4 p;
    p.x = pack4(rowbuf + base + 0, inv);
    p.y = pack4(rowbuf + base + 4, inv);
    p.z = pack4(rowbuf + base + 8, inv);
    p.w = pack4(rowbuf + base + 12, inv);
    *(uint4*)(wq + (size_t)o * K_DIM + base) = p;
    if (t == 0) sw[o] = amax * (1.0f / 127.0f);
  } else {
    // ---- X path ----
    const size_t m = blockIdx.x - N_DIM;
    const float* xr = x + m * K_DIM;
    float v[16];
    float amax = 0.f;
#pragma unroll
    for (int j = 0; j < 4; ++j) {
      float4 xv = *(const float4*)(xr + base + j * 4);
      float4 cv = *(const float4*)(cs + base + j * 4);
      v[j * 4 + 0] = xv.x * cv.x;
      v[j * 4 + 1] = xv.y * cv.y;
      v[j * 4 + 2] = xv.z * cv.z;
      v[j * 4 + 3] = xv.w * cv.w;
#pragma unroll
      for (int i = 0; i < 4; ++i) amax = fmaxf(amax, fabsf(v[j * 4 + i]));
    }
    amax = block_absmax(amax, red);
    amax = fmaxf(amax, 1e-20f);
    const float inv = 127.0f / amax;
    uint4 p;
    p.x = pack4(v + 0, inv);
    p.y = pack4(v + 4, inv);
    p.z = pack4(v + 8, inv);
    p.w = pack4(v + 12, inv);
    *(uint4*)(xq + m * K_DIM + base) = p;
    if (t == 0) sx[m] = amax * (1.0f / 127.0f);
  }
}

// ---- gemm: 32x32x32 i8 MFMA, 2 phases per K-tile ----
// 256x256 tile, BK=64, 8 waves (2M x 4N), per-wave 128x64 out as 4x2
// 32x32 fragments. Phase = {4-8 ds_read_b128 + 2 global_load_lds ->
// s_barrier -> setprio(1) 8 MFMA setprio(0) -> s_barrier}: 585-cyc MFMA
// window per phase per CU, matching the verified bf16 template geometry
// (the round-2 16x16 variant's 326-cyc window was too short to amortize
// phase overhead). Tri-buffer, counted vmcnt(4) once per tile, never 0
// in the main loop. Staging layout + swizzle byte-identical to the
// verified round-0/2 scheme: physical slot p of row r holds global chunk
// p ^ ((r>>1)&3).
// Frag layouts (guide §3): A/B input: row|col = lane&31, k-half = lane>>5
// (16 contiguous bytes); C/D: col = lane&31, row = (reg&3) + 8*(reg>>2)
// + 4*(lane>>5), reg in [0,16) — dtype-independent, m74/m101-verified.
#define BM 256
#define BN 256
#define BK 64
#define KTILES (K_DIM / BK)   // 64

__global__ __launch_bounds__(512, 2) void gemm_i8(
    const u8* __restrict__ A, const u8* __restrict__ B,
    const float* __restrict__ sx, const float* __restrict__ sw,
    const float* __restrict__ bias, float* __restrict__ out) {
  __shared__ __align__(16) u8 As[3][BM * BK];   // 3 x 16 KB
  __shared__ __align__(16) u8 Bs[3][BN * BK];   // 3 x 16 KB
  const int tid = threadIdx.x;
  const int lane = tid & 63;
  const int wave = tid >> 6;
  const int wm = wave >> 2;            // 0..1 -> 128 M-rows
  const int wn = wave & 3;             // 0..3 -> 64 N-cols
  const int l5 = lane & 31;
  const int hi = lane >> 5;            // k-half selector
  const int swz = (l5 >> 1) & 3;
  const int blockN = blockIdx.x * BN;
  const int blockM = blockIdx.y * BM;

  const char* Abase = (const char*)(A + (size_t)blockM * K_DIM);
  const char* Bbase = (const char*)(B + (size_t)blockN * K_DIM);

  // staging: 1024 16B chunks per matrix per tile, 2 per thread per matrix
  const int c0 = tid, c1 = tid + 512;
  const int kc0 = (c0 & 3) ^ ((c0 >> 3) & 3);
  const int kc1 = (c1 & 3) ^ ((c1 >> 3) & 3);
  const size_t gOff0 = (size_t)(c0 >> 2) * K_DIM + kc0 * 16;
  const size_t gOff1 = (size_t)(c1 >> 2) * K_DIM + kc1 * 16;
  const int dOff0 = c0 * 16, dOff1 = c1 * 16;

  // frag base addrs (k-half 0 chunk = hi ^ swz; k-half 1 = ^32 bytes)
  const int aoff = (wm * 128 + l5) * 64 + ((hi ^ swz) << 4);
  const int boff = (wn * 64 + l5) * 64 + ((hi ^ swz) << 4);

  intx16 acc[4][2];
#pragma unroll
  for (int i = 0; i < 4; ++i)
#pragma unroll
    for (int j = 0; j < 2; ++j) acc[i][j] = (intx16)0;

  // prologue: tile0 -> buf0, tile1 -> buf1; certify tile0, tile1 stays flying
  gload_lds16(Abase + gOff0, &As[0][dOff0]);
  gload_lds16(Abase + gOff1, &As[0][dOff1]);
  gload_lds16(Bbase + gOff0, &Bs[0][dOff0]);
  gload_lds16(Bbase + gOff1, &Bs[0][dOff1]);
  gload_lds16(Abase + gOff0 + BK, &As[1][dOff0]);
  gload_lds16(Abase + gOff1 + BK, &As[1][dOff1]);
  gload_lds16(Bbase + gOff0 + BK, &Bs[1][dOff0]);
  gload_lds16(Bbase + gOff1 + BK, &Bs[1][dOff1]);
  asm volatile("s_waitcnt vmcnt(4)" ::: "memory");
  asm volatile("s_barrier" ::: "memory");

  int bc = 0, bs = 2;
  for (int t = 0; t < KTILES; ++t) {
    const u8* Ab = &As[bc][0];
    const u8* Bb = &Bs[bc][0];
    u8* Aw = &As[bs][0];
    u8* Bw = &Bs[bs][0];
    const size_t koff2 = (size_t)(t + 2) * BK;
    const bool pf = (t + 2 < KTILES);

    // ---- phase 0: B frags + A(0,1) | stage half0 of t+2 ----
    intx4 b00 = *(const intx4*)(Bb + boff);
    intx4 b01 = *(const intx4*)(Bb + (boff ^ 32));
    intx4 b10 = *(const intx4*)(Bb + boff + 2048);
    intx4 b11 = *(const intx4*)(Bb + (boff ^ 32) + 2048);
    intx4 a00 = *(const intx4*)(Ab + aoff);
    intx4 a01 = *(const intx4*)(Ab + (aoff ^ 32));
    intx4 a10 = *(const intx4*)(Ab + aoff + 2048);
    intx4 a11 = *(const intx4*)(Ab + (aoff ^ 32) + 2048);
    if (pf) {
      gload_lds16(Abase + gOff0 + koff2, Aw + dOff0);
      gload_lds16(Bbase + gOff0 + koff2, Bw + dOff0);
    }
    asm volatile("s_barrier" ::: "memory");
    __builtin_amdgcn_s_setprio(1);
    acc[0][0] = __builtin_amdgcn_mfma_i32_32x32x32_i8(a00, b00, acc[0][0], 0, 0, 0);
    acc[0][1] = __builtin_amdgcn_mfma_i32_32x32x32_i8(a00, b10, acc[0][1], 0, 0, 0);
    acc[1][0] = __builtin_amdgcn_mfma_i32_32x32x32_i8(a10, b00, acc[1][0], 0, 0, 0);
    acc[1][1] = __builtin_amdgcn_mfma_i32_32x32x32_i8(a10, b10, acc[1][1], 0, 0, 0);
    acc[0][0] = __builtin_amdgcn_mfma_i32_32x32x32_i8(a01, b01, acc[0][0], 0, 0, 0);
    acc[0][1] = __builtin_amdgcn_mfma_i32_32x32x32_i8(a01, b11, acc[0][1], 0, 0, 0);
    acc[1][0] = __builtin_amdgcn_mfma_i32_32x32x32_i8(a11, b01, acc[1][0], 0, 0, 0);
    acc[1][1] = __builtin_amdgcn_mfma_i32_32x32x32_i8(a11, b11, acc[1][1], 0, 0, 0);
    __builtin_amdgcn_s_setprio(0);
    asm volatile("s_barrier" ::: "memory");

    // ---- phase 1: A(2,3) | stage half1 of t+2 | counted vmcnt ----
    intx4 a20 = *(const intx4*)(Ab + aoff + 4096);
    intx4 a21 = *(const intx4*)(Ab + (aoff ^ 32) + 4096);
    intx4 a30 = *(const intx4*)(Ab + aoff + 6144);
    intx4 a31 = *(const intx4*)(Ab + (aoff ^ 32) + 6144);
    if (pf) {
      gload_lds16(Abase + gOff1 + koff2, Aw + dOff1);
      gload_lds16(Bbase + gOff1 + koff2, Bw + dOff1);
    }
    asm volatile("s_barrier" ::: "memory");
    __builtin_amdgcn_s_setprio(1);
    acc[2][0] = __builtin_amdgcn_mfma_i32_32x32x32_i8(a20, b00, acc[2][0], 0, 0, 0);
    acc[2][1] = __builtin_amdgcn_mfma_i32_32x32x32_i8(a20, b10, acc[2][1], 0, 0, 0);
    acc[3][0] = __builtin_amdgcn_mfma_i32_32x32x32_i8(a30, b00, acc[3][0], 0, 0, 0);
    acc[3][1] = __builtin_amdgcn_mfma_i32_32x32x32_i8(a30, b10, acc[3][1], 0, 0, 0);
    acc[2][0] = __builtin_amdgcn_mfma_i32_32x32x32_i8(a21, b01, acc[2][0], 0, 0, 0);
    acc[2][1] = __builtin_amdgcn_mfma_i32_32x32x32_i8(a21, b11, acc[2][1], 0, 0, 0);
    acc[3][0] = __builtin_amdgcn_mfma_i32_32x32x32_i8(a31, b01, acc[3][0], 0, 0, 0);
    acc[3][1] = __builtin_amdgcn_mfma_i32_32x32x32_i8(a31, b11, acc[3][1], 0, 0, 0);
    __builtin_amdgcn_s_setprio(0);
    if (t < KTILES - 2) {
      asm volatile("s_waitcnt vmcnt(4)" ::: "memory");   // t+1 certified
    } else if (t == KTILES - 2) {
      asm volatile("s_waitcnt vmcnt(0)" ::: "memory");   // drain
    }
    if (t < KTILES - 1) asm volatile("s_barrier" ::: "memory");

    bc = (bc == 2) ? 0 : bc + 1;
    bs = (bs == 2) ? 0 : bs + 1;
  }

  // epilogue: col = lane&31, row = (reg&3) + 8*(reg>>2) + 4*hi
#pragma unroll
  for (int ni = 0; ni < 2; ++ni) {
    const int col = blockN + wn * 64 + ni * 32 + l5;
    const float swv = sw[col];
    const float bv = bias[col];
#pragma unroll
    for (int mi = 0; mi < 4; ++mi) {
      const int row0 = blockM + wm * 128 + mi * 32 + 4 * hi;
#pragma unroll
      for (int rg = 0; rg < 4; ++rg) {
#pragma unroll
        for (int rr = 0; rr < 4; ++rr) {
          const int row = row0 + rg * 8 + rr;
          const float s = sx[row] * swv;
          out[(size_t)row * N_DIM + col] = (float)acc[mi][ni][rg * 4 + rr] * s + bv;
        }
      }
    }
  }
}

extern "C" void kernel_launch(void* const* d_in, const int* in_sizes, int n_in,
                              void* d_out, int out_size, void* d_ws, size_t ws_size,
                              hipStream_t stream) {
  const float* x      = (const float*)d_in[0];
  const float* cs     = (const float*)d_in[1];
  const u32*   qw     = (const u32*)d_in[2];
  const int*   perm   = (const int*)d_in[3];
  const float* scales = (const float*)d_in[4];
  const float* zeros  = (const float*)d_in[5];
  const float* bias   = (const float*)d_in[6];
  float* out = (float*)d_out;

  u8* xq = (u8*)d_ws;                               // 32 MiB: M*K i8 (natural)
  u8* wq = xq + (size_t)M_DIM * K_DIM;              // 16 MiB: N*K i8 (perm-scattered)
  float* sx = (float*)(wq + (size_t)N_DIM * K_DIM); // 32 KiB
  float* sw = sx + M_DIM;                           // 16 KiB

  hipLaunchKernelGGL(prep_all, dim3(N_DIM + M_DIM), dim3(256), 0, stream,
                     x, cs, qw, perm, scales, zeros, xq, wq, sx, sw);
  hipLaunchKernelGGL(gemm_i8, dim3(N_DIM / BN, M_DIM / BM), dim3(512), 0,
                     stream, xq, wq, sx, sw, bias, out);
}